// Round 1
// baseline (1664.429 us; speedup 1.0000x reference)
//
#include <hip/hip_runtime.h>

// CHIVE clockwork RNN, fp32.
// Mapping: block = 256 threads = 8 batch chains x 32 hidden lanes.
// grid = 256 blocks -> B=2048. Weights (columns) in registers, state in LDS
// (wave-private per 32-lane group), inputs staged in double-buffered LDS
// chunks of 16 timesteps with register prefetch.

constexpr int TS  = 2048;  // timesteps
constexpr int B   = 2048;  // batch
constexpr int HH  = 32;    // hidden
constexpr int CH  = 16;    // timesteps per staged chunk
constexpr int NCH = TS / CH;
constexpr int BPB = 8;     // batch per block

__device__ __forceinline__ float fast_tanh(float x) {
    x = fminf(fmaxf(x, -9.0f), 9.0f);
    float e = __expf(2.0f * x);
    return (e - 1.0f) * __builtin_amdgcn_rcpf(e + 1.0f);
}

__global__ __launch_bounds__(256, 1)
void chive_rnn(const float* __restrict__ frnn, const float* __restrict__ phrnn,
               const float* __restrict__ syl,
               const float* __restrict__ Wxf, const float* __restrict__ Whf,
               const float* __restrict__ bf,
               const float* __restrict__ Wxp, const float* __restrict__ Whp,
               const float* __restrict__ bp,
               const float* __restrict__ Wxs, const float* __restrict__ Whs,
               const float* __restrict__ bs,
               const int* __restrict__ fclock, const int* __restrict__ pclock,
               const int* __restrict__ sfreq, float* __restrict__ out)
{
    __shared__ __align__(16) float xfb[2][CH][BPB * 8];
    __shared__ __align__(16) float xpb[2][CH][BPB * 8];
    __shared__ __align__(16) float xsb[2][CH][BPB * 24];
    __shared__ __align__(16) float hf[BPB][HH];
    __shared__ __align__(16) float hp[BPB][HH];
    __shared__ __align__(16) float hs[3][BPB][HH];
    __shared__ int gates[TS];

    const int tid = threadIdx.x;
    const int j   = tid & 31;   // hidden index
    const int g   = tid >> 5;   // batch-in-block
    const int b0  = blockIdx.x * BPB;

    // ---- per-lane weight columns (stay in VGPRs: all loops fully unrolled) ----
    float wxf[8], whf_r[32], wxp[8], whp_r[32], wxs_r[32], whs_r[32];
#pragma unroll
    for (int i = 0; i < 8;  i++) wxf[i]   = Wxf[i * HH + j];
#pragma unroll
    for (int i = 0; i < 32; i++) whf_r[i] = Whf[i * HH + j];
#pragma unroll
    for (int i = 0; i < 8;  i++) wxp[i]   = Wxp[i * HH + j];
#pragma unroll
    for (int i = 0; i < 32; i++) whp_r[i] = Whp[i * HH + j];
#pragma unroll
    for (int i = 0; i < 32; i++) wxs_r[i] = Wxs[i * HH + j];
#pragma unroll
    for (int i = 0; i < 32; i++) whs_r[i] = Whs[i * HH + j];
    const float bfj = bf[j], bpj = bp[j], bsj = bs[j];

    // ---- chunk staging (register prefetch -> LDS double buffer) ----
    float4 rf, rp, rs0, rs1, rs2;
    const int tl = tid >> 4;   // 0..15: timestep within chunk this thread loads
    const int q  = tid & 15;   // 0..15: float4 slot within the row

    auto load_chunk = [&](int ch) {
        const size_t t  = (size_t)ch * CH + tl;
        const float* fb = frnn  + (t * B + b0) * 8;
        const float* pb = phrnn + (t * B + b0) * 8;
        const float* sb = syl   + (t * B + b0) * 24;
        rf  = *(const float4*)(fb + q * 4);
        rp  = *(const float4*)(pb + q * 4);
        rs0 = *(const float4*)(sb + q * 4);
        rs1 = *(const float4*)(sb + 64 + q * 4);
        rs2 = *(const float4*)(sb + 128 + q * 4);
    };
    auto store_chunk = [&](int buf) {
        *(float4*)&xfb[buf][tl][q * 4]       = rf;
        *(float4*)&xpb[buf][tl][q * 4]       = rp;
        *(float4*)&xsb[buf][tl][q * 4]       = rs0;
        *(float4*)&xsb[buf][tl][64 + q * 4]  = rs1;
        *(float4*)&xsb[buf][tl][128 + q * 4] = rs2;
    };

    load_chunk(0);

    // ---- gate precompute: upd_f / upd_p / upd_s per timestep ----
    for (int i = tid; i < TS; i += 256) {
        int mf = fclock[i] + 1;
        int mp = pclock[i] + 1;
        int v = 0;
        if ((i % mf) == 0)  v |= 1;
        if ((i % mp) == 0)  v |= 2;
        if (sfreq[i] == 1)  v |= 4;
        gates[i] = v;
    }

    // ---- state init (each lane owns (g,j) of every channel) ----
    hf[g][j] = 0.f; hp[g][j] = 0.f;
    hs[0][g][j] = 0.f; hs[1][g][j] = 0.f; hs[2][g][j] = 0.f;

    store_chunk(0);
    __syncthreads();

    int cur = 0;
#pragma unroll 1
    for (int ch = 0; ch < NCH; ch++) {
        if (ch + 1 < NCH) load_chunk(ch + 1);   // prefetch next chunk into regs

#pragma unroll 1
        for (int c = 0; c < CH; c++) {
            const int t  = ch * CH + c;
            const int gt = __builtin_amdgcn_readfirstlane(gates[t]);

            // ---------- f cell ----------
            if (gt & 1) {
                float4 a = {bfj, 0.f, 0.f, 0.f};
                const float4* xv = (const float4*)&xfb[cur][c][g * 8];
                float4 x0 = xv[0], x1 = xv[1];
                a.x = fmaf(x0.x, wxf[0], a.x); a.y = fmaf(x0.y, wxf[1], a.y);
                a.z = fmaf(x0.z, wxf[2], a.z); a.w = fmaf(x0.w, wxf[3], a.w);
                a.x = fmaf(x1.x, wxf[4], a.x); a.y = fmaf(x1.y, wxf[5], a.y);
                a.z = fmaf(x1.z, wxf[6], a.z); a.w = fmaf(x1.w, wxf[7], a.w);
#pragma unroll
                for (int kk = 0; kk < 8; kk++) {
                    float4 h4 = *(const float4*)&hf[g][kk * 4];
                    a.x = fmaf(h4.x, whf_r[kk*4+0], a.x);
                    a.y = fmaf(h4.y, whf_r[kk*4+1], a.y);
                    a.z = fmaf(h4.z, whf_r[kk*4+2], a.z);
                    a.w = fmaf(h4.w, whf_r[kk*4+3], a.w);
                }
                hf[g][j] = fast_tanh((a.x + a.y) + (a.z + a.w));
            }

            // ---------- p cell ----------
            if (gt & 2) {
                float4 a = {bpj, 0.f, 0.f, 0.f};
                const float4* xv = (const float4*)&xpb[cur][c][g * 8];
                float4 x0 = xv[0], x1 = xv[1];
                a.x = fmaf(x0.x, wxp[0], a.x); a.y = fmaf(x0.y, wxp[1], a.y);
                a.z = fmaf(x0.z, wxp[2], a.z); a.w = fmaf(x0.w, wxp[3], a.w);
                a.x = fmaf(x1.x, wxp[4], a.x); a.y = fmaf(x1.y, wxp[5], a.y);
                a.z = fmaf(x1.z, wxp[6], a.z); a.w = fmaf(x1.w, wxp[7], a.w);
#pragma unroll
                for (int kk = 0; kk < 8; kk++) {
                    float4 h4 = *(const float4*)&hp[g][kk * 4];
                    a.x = fmaf(h4.x, whp_r[kk*4+0], a.x);
                    a.y = fmaf(h4.y, whp_r[kk*4+1], a.y);
                    a.z = fmaf(h4.z, whp_r[kk*4+2], a.z);
                    a.w = fmaf(h4.w, whp_r[kk*4+3], a.w);
                }
                hp[g][j] = fast_tanh((a.x + a.y) + (a.z + a.w));
            }

            // ---------- syl cell: 3 slices, x = {hf_new, hp_new, x_syl} ----------
            if (gt & 4) {
                float4 a0 = {bsj, 0.f, 0.f, 0.f};
                float4 a1 = {bsj, 0.f, 0.f, 0.f};
                float4 a2 = {bsj, 0.f, 0.f, 0.f};
                // x parts for slices 0,1 (new hf / hp), shared Wx_s weights
#pragma unroll
                for (int kk = 0; kk < 8; kk++) {
                    float4 hf4 = *(const float4*)&hf[g][kk * 4];
                    float4 hp4 = *(const float4*)&hp[g][kk * 4];
                    float w0 = wxs_r[kk*4+0], w1 = wxs_r[kk*4+1];
                    float w2 = wxs_r[kk*4+2], w3 = wxs_r[kk*4+3];
                    a0.x = fmaf(hf4.x, w0, a0.x); a0.y = fmaf(hf4.y, w1, a0.y);
                    a0.z = fmaf(hf4.z, w2, a0.z); a0.w = fmaf(hf4.w, w3, a0.w);
                    a1.x = fmaf(hp4.x, w0, a1.x); a1.y = fmaf(hp4.y, w1, a1.y);
                    a1.z = fmaf(hp4.z, w2, a1.z); a1.w = fmaf(hp4.w, w3, a1.w);
                }
                // x part for slice 2: syl input (24 real floats, pad rows 24..31 are zero)
#pragma unroll
                for (int kk = 0; kk < 6; kk++) {
                    float4 x4 = *(const float4*)&xsb[cur][c][g * 24 + kk * 4];
                    a2.x = fmaf(x4.x, wxs_r[kk*4+0], a2.x);
                    a2.y = fmaf(x4.y, wxs_r[kk*4+1], a2.y);
                    a2.z = fmaf(x4.z, wxs_r[kk*4+2], a2.z);
                    a2.w = fmaf(x4.w, wxs_r[kk*4+3], a2.w);
                }
                // h parts (old hs state)
#pragma unroll
                for (int kk = 0; kk < 8; kk++) {
                    float4 h0 = *(const float4*)&hs[0][g][kk * 4];
                    float4 h1 = *(const float4*)&hs[1][g][kk * 4];
                    float4 h2 = *(const float4*)&hs[2][g][kk * 4];
                    float w0 = whs_r[kk*4+0], w1 = whs_r[kk*4+1];
                    float w2 = whs_r[kk*4+2], w3 = whs_r[kk*4+3];
                    a0.x = fmaf(h0.x, w0, a0.x); a0.y = fmaf(h0.y, w1, a0.y);
                    a0.z = fmaf(h0.z, w2, a0.z); a0.w = fmaf(h0.w, w3, a0.w);
                    a1.x = fmaf(h1.x, w0, a1.x); a1.y = fmaf(h1.y, w1, a1.y);
                    a1.z = fmaf(h1.z, w2, a1.z); a1.w = fmaf(h1.w, w3, a1.w);
                    a2.x = fmaf(h2.x, w0, a2.x); a2.y = fmaf(h2.y, w1, a2.y);
                    a2.z = fmaf(h2.z, w2, a2.z); a2.w = fmaf(h2.w, w3, a2.w);
                }
                hs[0][g][j] = fast_tanh((a0.x + a0.y) + (a0.z + a0.w));
                hs[1][g][j] = fast_tanh((a1.x + a1.y) + (a1.z + a1.w));
                hs[2][g][j] = fast_tanh((a2.x + a2.y) + (a2.z + a2.w));
            }
        }

        if (ch + 1 < NCH) store_chunk(cur ^ 1);
        __syncthreads();
        cur ^= 1;
    }

    // ---- output: h_s final, [3, B, H] ----
    const int b = b0 + g;
    out[((size_t)0 * B + b) * HH + j] = hs[0][g][j];
    out[((size_t)1 * B + b) * HH + j] = hs[1][g][j];
    out[((size_t)2 * B + b) * HH + j] = hs[2][g][j];
}

extern "C" void kernel_launch(void* const* d_in, const int* in_sizes, int n_in,
                              void* d_out, int out_size, void* d_ws, size_t ws_size,
                              hipStream_t stream) {
    const float* frnn  = (const float*)d_in[0];
    const float* phrnn = (const float*)d_in[1];
    const float* syl   = (const float*)d_in[2];
    const float* Wxf   = (const float*)d_in[3];
    const float* Whf   = (const float*)d_in[4];
    const float* bf    = (const float*)d_in[5];
    const float* Wxp   = (const float*)d_in[6];
    const float* Whp   = (const float*)d_in[7];
    const float* bp    = (const float*)d_in[8];
    const float* Wxs   = (const float*)d_in[9];
    const float* Whs   = (const float*)d_in[10];
    const float* bs    = (const float*)d_in[11];
    const int* fclock  = (const int*)d_in[12];
    const int* pclock  = (const int*)d_in[13];
    const int* sfreq   = (const int*)d_in[14];
    float* out = (float*)d_out;

    dim3 grid(B / BPB);   // 256 blocks
    dim3 block(256);
    chive_rnn<<<grid, block, 0, stream>>>(frnn, phrnn, syl,
                                          Wxf, Whf, bf, Wxp, Whp, bp,
                                          Wxs, Whs, bs,
                                          fclock, pclock, sfreq, out);
}